// Round 6
// baseline (172.483 us; speedup 1.0000x reference)
//
#include <hip/hip_runtime.h>
#include <hip/hip_bf16.h>

#define MM 256
#define KK 4096
#define NN 32000
#define BN 64
#define BK 128
#define NT (KK / BK)   // 32 K-steps

typedef __bf16 bf16x8 __attribute__((ext_vector_type(8)));
typedef float f32x4 __attribute__((ext_vector_type(4)));

__device__ __forceinline__ unsigned pk(float a, float b) {
    unsigned short lo = __builtin_bit_cast(unsigned short, __float2bfloat16(a));
    unsigned short hi = __builtin_bit_cast(unsigned short, __float2bfloat16(b));
    return (unsigned)lo | ((unsigned)hi << 16);
}

__device__ __forceinline__ void dma16(const unsigned short* g, unsigned short* l) {
    __builtin_amdgcn_global_load_lds(
        (const __attribute__((address_space(1))) unsigned int*)g,
        (__attribute__((address_space(3))) unsigned int*)l, 16, 0, 0);
}

// xb layout: tile-major [t][row r][chunk s], chunk = 8 ushorts, s in 0..15,
// pre-swizzled: chunk s of row r holds x[r][t*128 + (s ^ (r&15))*8 .. +8).
// gemm DMAs tile t LINEARLY into LDS; swizzled ds_read recovers fragments.
__global__ void cvt_x_kernel(const float* __restrict__ x, unsigned short* __restrict__ xb) {
    int g = blockIdx.x * 256 + threadIdx.x;   // chunk id, 131072 total
    int t = g >> 12;          // 0..31
    int d = g & 4095;
    int r = d >> 4;           // 0..255
    int s = d & 15;
    int c = s ^ (r & 15);
    const float* p = x + r * KK + t * BK + c * 8;
    float4 a = *(const float4*)p;
    float4 b = *(const float4*)(p + 4);
    uint4 v;
    v.x = pk(a.x, a.y); v.y = pk(a.z, a.w);
    v.z = pk(b.x, b.y); v.w = pk(b.z, b.w);
    *(uint4*)(xb + (size_t)g * 8) = v;
}

// C[m][n] = sum_k x[m][k] * w[n][k]. BM=256 (W fetched exactly once), BN=64,
// BK=128 -> each W row is consumed in 512B contiguous chunks per step
// (vs 256B before): tests the DRAM-granularity theory. grid=500, 512 thr =
// 8 waves (4M x 2N). LDS 160KB: x dbuf 2x64KB (global_load_lds, pre-swizzled
// ws) + W dbuf 2x16KB (fp32->reg depth-2 -> pk -> ds_write). One raw
// s_barrier/step; own dma drained via counted vmcnt BEFORE barrier; W(t+1) +
// dma(t+1) always in flight (never vmcnt 0 in loop).
template <bool XB>
__global__ __launch_bounds__(512, 2) void gemm_kernel(
    const unsigned short* __restrict__ xb, const float* __restrict__ xf,
    const float* __restrict__ w, float* __restrict__ out) {
    __shared__ unsigned short xs[2][32768];  // 2 x 64 KB
    __shared__ unsigned short wt[2][8192];   // 2 x 16 KB

    const int tid  = threadIdx.x;
    const int lane = tid & 63;
    const int wid  = tid >> 6;    // 0..7
    const int wm   = wid >> 1;    // 0..3 -> 64-row slice
    const int wn   = wid & 1;     // 0..1 -> 32-col slice
    const int l15  = lane & 15;
    const int lg   = lane >> 4;
    const int n0   = blockIdx.x * BN;

    // W staging: thread -> row tid>>3 (0..63), 16 consecutive floats (64B)
    const int wrow  = tid >> 3;
    const int wslot = tid & 7;    // float offset wslot*16
    const float* wsrc = w + (size_t)(n0 + wrow) * KK + wslot * 16;
    const int ws0 = wslot * 2;    // first of 2 bf16 chunks

    f32x4 acc[4][2];
#pragma unroll
    for (int i = 0; i < 4; ++i)
#pragma unroll
        for (int j = 0; j < 2; ++j) acc[i][j] = f32x4{0.f, 0.f, 0.f, 0.f};

    auto compute = [&](int pb) {
        __builtin_amdgcn_s_setprio(1);
#pragma unroll
        for (int kf = 0; kf < 4; ++kf) {
            const int c = kf * 4 + lg;   // chunk 0..15
            uint4 bfr[2];
#pragma unroll
            for (int ni = 0; ni < 2; ++ni) {
                const int r = wn * 32 + ni * 16 + l15;
                bfr[ni] = *(const uint4*)&wt[pb][r * 128 + ((c ^ (r & 15)) * 8)];
            }
            uint4 af[4];
#pragma unroll
            for (int mi = 0; mi < 4; ++mi) {
                const int r = wm * 64 + mi * 16 + l15;
                af[mi] = *(const uint4*)&xs[pb][r * 128 + ((c ^ (r & 15)) * 8)];
            }
#pragma unroll
            for (int mi = 0; mi < 4; ++mi)
#pragma unroll
                for (int ni = 0; ni < 2; ++ni)
                    acc[mi][ni] = __builtin_amdgcn_mfma_f32_16x16x32_bf16(
                        __builtin_bit_cast(bf16x8, af[mi]),
                        __builtin_bit_cast(bf16x8, bfr[ni]), acc[mi][ni], 0, 0, 0);
        }
        __builtin_amdgcn_s_setprio(0);
    };

    if constexpr (!XB) {
        // correctness fallback (ws too small): direct global reads, no LDS
#pragma unroll 1
        for (int t = 0; t < KK / 32; ++t) {
            const int k = t * 32 + lg * 8;
            uint4 bfr[2];
#pragma unroll
            for (int ni = 0; ni < 2; ++ni) {
                const float* p = w + (size_t)(n0 + wn * 32 + ni * 16 + l15) * KK + k;
                float4 a0 = *(const float4*)p;
                float4 a1 = *(const float4*)(p + 4);
                bfr[ni].x = pk(a0.x, a0.y); bfr[ni].y = pk(a0.z, a0.w);
                bfr[ni].z = pk(a1.x, a1.y); bfr[ni].w = pk(a1.z, a1.w);
            }
#pragma unroll
            for (int mi = 0; mi < 4; ++mi) {
                const float* p = xf + (size_t)(wm * 64 + mi * 16 + l15) * KK + k;
                float4 a0 = *(const float4*)p;
                float4 a1 = *(const float4*)(p + 4);
                uint4 af;
                af.x = pk(a0.x, a0.y); af.y = pk(a0.z, a0.w);
                af.z = pk(a1.x, a1.y); af.w = pk(a1.z, a1.w);
#pragma unroll
                for (int ni = 0; ni < 2; ++ni)
                    acc[mi][ni] = __builtin_amdgcn_mfma_f32_16x16x32_bf16(
                        __builtin_bit_cast(bf16x8, af),
                        __builtin_bit_cast(bf16x8, bfr[ni]), acc[mi][ni], 0, 0, 0);
            }
        }
    } else {
        float4 wrA[4], wrB[4];

        auto issueW = [&](int t, float4 (&wr)[4]) {
            const float* p = wsrc + t * BK;
#pragma unroll
            for (int i = 0; i < 4; ++i) wr[i] = *(const float4*)(p + i * 4);
        };
        auto stageW = [&](int pb, float4 (&wr)[4]) {
            uint4 v0, v1;
            v0.x = pk(wr[0].x, wr[0].y); v0.y = pk(wr[0].z, wr[0].w);
            v0.z = pk(wr[1].x, wr[1].y); v0.w = pk(wr[1].z, wr[1].w);
            v1.x = pk(wr[2].x, wr[2].y); v1.y = pk(wr[2].z, wr[2].w);
            v1.z = pk(wr[3].x, wr[3].y); v1.w = pk(wr[3].z, wr[3].w);
            *(uint4*)&wt[pb][wrow * 128 + ((ws0 ^ (wrow & 15)) * 8)]       = v0;
            *(uint4*)&wt[pb][wrow * 128 + (((ws0 + 1) ^ (wrow & 15)) * 8)] = v1;
        };
        auto issue_dma = [&](int t, int pb) {
            // 8 rounds x 512 thr x 16B = 64 KB; wave-uniform base + lane*16B
#pragma unroll
            for (int j = 0; j < 8; ++j) {
                const unsigned short* gp =
                    xb + (size_t)t * 32768 + j * 4096 + wid * 512 + lane * 8;
                unsigned short* lp = &xs[pb][j * 4096 + wid * 512];
                dma16(gp, lp);
            }
        };

        // steady state on entry: outstanding = W(t)[4] old, dma(t)[8], W(t+1)[4]
        auto tile_body = [&](int pb, int t, float4 (&wr)[4]) {
            stageW(pb, wr);                        // compiler: vmcnt(12) for W(t)
            __builtin_amdgcn_sched_barrier(0);
            asm volatile("s_waitcnt vmcnt(4)" ::: "memory");   // drain dma(t); keep W(t+1)
            asm volatile("s_waitcnt lgkmcnt(0)" ::: "memory"); // ds_writes visible
            __builtin_amdgcn_sched_barrier(0);
            __builtin_amdgcn_s_barrier();          // xs[pb], wt[pb] published
            const int tn = (t + 1 < NT) ? t + 1 : NT - 1;
            issue_dma(tn, pb ^ 1);                 // safe: compute(t-1) done block-wide
            __builtin_amdgcn_sched_barrier(0);
            const int tw = (t + 2 < NT) ? t + 2 : NT - 1;
            issueW(tw, wr);
            __builtin_amdgcn_sched_barrier(0);
            compute(pb);
        };

        issueW(0, wrA);
        issue_dma(0, 0);
        issueW(1, wrB);

#pragma unroll 1
        for (int t = 0; t < NT; t += 2) {
            tile_body(0, t, wrA);
            tile_body(1, t + 1, wrB);
        }
        asm volatile("s_waitcnt vmcnt(0)" ::: "memory");  // drain tail junk
    }

    // epilogue: per 16x16 tile, col = lane&15, row = (lane>>4)*4 + v
#pragma unroll
    for (int mi = 0; mi < 4; ++mi)
#pragma unroll
        for (int ni = 0; ni < 2; ++ni) {
            const int rowb = wm * 64 + mi * 16 + lg * 4;
            const int col  = n0 + wn * 32 + ni * 16 + l15;
#pragma unroll
            for (int v = 0; v < 4; ++v)
                out[(size_t)(rowb + v) * NN + col] = acc[mi][ni][v];
        }
}

extern "C" void kernel_launch(void* const* d_in, const int* in_sizes, int n_in,
                              void* d_out, int out_size, void* d_ws, size_t ws_size,
                              hipStream_t stream) {
    const float* x = (const float*)d_in[0];
    const float* w = (const float*)d_in[1];
    float* out = (float*)d_out;
    unsigned short* xb = (unsigned short*)d_ws;

    if (ws_size >= (size_t)MM * KK * sizeof(unsigned short)) {
        cvt_x_kernel<<<512, 256, 0, stream>>>(x, xb);
        gemm_kernel<true><<<NN / BN, 512, 0, stream>>>(xb, x, w, out);
    } else {
        gemm_kernel<false><<<NN / BN, 512, 0, stream>>>(nullptr, x, w, out);
    }
}